// Round 1
// baseline (1014.575 us; speedup 1.0000x reference)
//
#include <hip/hip_runtime.h>
#include <stdint.h>

typedef __attribute__((ext_vector_type(4))) float f32x4;
typedef __attribute__((ext_vector_type(8))) short s16x8;

#define DEVFN static __device__ __forceinline__

constexpr int C = 384;
constexpr int HIMG = 128, WIMG = 128;
constexpr int HW = HIMG * WIMG;
constexpr int HEADS = 12;
constexpr int INNER = 384;
constexpr float EPS = 1e-5f;
constexpr float QSCALE = 0.17677669529663687f;  // 1/sqrt(32)

// ---------------- LDS layout (bytes) ----------------
constexpr int XN_STR = 392;                        // shorts per row (384 + 8 pad -> 2-way bank alias on b128 reads)
constexpr int XN_OFF = 0;                          // bf16 [64][392]
constexpr int XN_BYTES = 64 * XN_STR * 2;          // 50176
constexpr int SKN_OFF = XN_OFF + XN_BYTES;         // 50176
constexpr int QH_OFF = SKN_OFF + XN_BYTES;         // 100352  bf16 [64][40]  (also OH)
constexpr int QH_STR = 40;
constexpr int KH_OFF = QH_OFF + 64 * QH_STR * 2;   // 105472  bf16 [64][40]
constexpr int VT_OFF = KH_OFF + 64 * QH_STR * 2;   // 110592  bf16 [32][72]
constexpr int VT_STR = 72;
constexpr int P_OFF = VT_OFF + 32 * VT_STR * 2;    // 115200  bf16 [64][72]
constexpr int P_STR = 72;
constexpr int LDS_BYTES = P_OFF + 64 * P_STR * 2;  // 124416
constexpr int RED_OFF = P_OFF;                     // f32 [8][64][2] during LN (4 KB)
constexpr int STATS_OFF = VT_OFF;                  // f32 [64][2] during LN
constexpr int OUTF_STR = 385;                      // f32 stride for epilogue transpose (overlays XN+SKN)

DEVFN unsigned short f2bf(float f) {
  union { float f; unsigned int u; } v; v.f = f;
  unsigned int r = v.u + 0x7fffu + ((v.u >> 16) & 1u);  // RNE
  return (unsigned short)(r >> 16);
}
DEVFN float bf2f(unsigned int h) {
  union { unsigned int u; float f; } v; v.u = h << 16;
  return v.f;
}
DEVFN f32x4 MFMA(s16x8 a, s16x8 b, f32x4 c) {
  return __builtin_amdgcn_mfma_f32_16x16x32_bf16(a, b, c, 0, 0, 0);
}

__global__ void cvt_bf16_kernel(const float* __restrict__ src, unsigned short* __restrict__ dst, int n) {
  int i = (blockIdx.x * blockDim.x + threadIdx.x) * 4;
  if (i + 3 < n) {
    f32x4 v = *(const f32x4*)(src + i);
    unsigned int lo = (unsigned int)f2bf(v[0]) | ((unsigned int)f2bf(v[1]) << 16);
    unsigned int hi = (unsigned int)f2bf(v[2]) | ((unsigned int)f2bf(v[3]) << 16);
    unsigned int* d = (unsigned int*)(dst + i);
    d[0] = lo; d[1] = hi;
  }
}

__launch_bounds__(256, 1)
__global__ void fused_win_attn(
    const float* __restrict__ x, const float* __restrict__ skip,
    const float* __restrict__ gq, const float* __restrict__ bq,
    const float* __restrict__ gkv, const float* __restrict__ bkv,
    const unsigned short* __restrict__ wqb, const unsigned short* __restrict__ wkvb,
    const unsigned short* __restrict__ woutb, const float* __restrict__ bout,
    float* __restrict__ out) {
  extern __shared__ char smem[];
  const int tid = threadIdx.x;
  const int lane = tid & 63;
  const int wv = tid >> 6;        // wave 0..3
  const int l15 = lane & 15;
  const int lg = lane >> 4;       // 0..3
  const int kco = lg * 8;         // k-chunk element offset (shorts) inside a K=32 step

  const int win = blockIdx.x;     // 2048 windows: b*256 + wh*16 + ww
  const int bimg = win >> 8;
  const int wh = (win >> 4) & 15;
  const int wwi = win & 15;
  const int Y0 = wh * 8, X0 = wwi * 8;
  const size_t img_off = (size_t)bimg * C * HW;

  const f32x4 fzero = {0.f, 0.f, 0.f, 0.f};

  // ---------------- channel LayerNorm: x -> XN (bf16), skip -> SKN (bf16) ----------------
  for (int tt = 0; tt < 2; ++tt) {
    const float* src = tt ? skip : x;
    const float* gg  = tt ? gkv : gq;
    const float* bb  = tt ? bkv : bq;
    unsigned short* xn = (unsigned short*)(smem + (tt ? SKN_OFF : XN_OFF));

    // pass 1: each thread sums 48 channels for 2 pixels; stash raw bf16 in LDS
    const int half = lane >> 5;          // channel parity
    const int px2 = lane & 31;           // pixel pair id
    const int yy = px2 >> 2;             // 0..7
    const int xh = px2 & 3;              // x = 2*xh
    const int p0 = yy * 8 + xh * 2;      // token index of first pixel
    float s0 = 0.f, s1 = 0.f, q0 = 0.f, q1 = 0.f;
    const float* gbase = src + img_off + (size_t)(Y0 + yy) * WIMG + X0 + xh * 2;
    for (int i = 0; i < 48; ++i) {
      int c = wv * 96 + half + 2 * i;
      float2 v = *(const float2*)(gbase + (size_t)c * HW);
      s0 += v.x; s1 += v.y;
      q0 += v.x * v.x; q1 += v.y * v.y;
      xn[p0 * XN_STR + c] = f2bf(v.x);
      xn[(p0 + 1) * XN_STR + c] = f2bf(v.y);
    }
    float* red = (float*)(smem + RED_OFF);
    int gh = wv * 2 + half;
    red[(gh * 64 + p0) * 2 + 0] = s0;
    red[(gh * 64 + p0) * 2 + 1] = q0;
    red[(gh * 64 + p0 + 1) * 2 + 0] = s1;
    red[(gh * 64 + p0 + 1) * 2 + 1] = q1;
    __syncthreads();
    // stats per pixel
    if (tid < 64) {
      float sm = 0.f, sq = 0.f;
      for (int g2 = 0; g2 < 8; ++g2) { sm += red[(g2 * 64 + tid) * 2]; sq += red[(g2 * 64 + tid) * 2 + 1]; }
      float mean = sm * (1.f / 384.f);
      float var = sq * (1.f / 384.f) - mean * mean;
      float* st = (float*)(smem + STATS_OFF);
      st[tid * 2] = mean;
      st[tid * 2 + 1] = 1.f / sqrtf(var + EPS);
    }
    __syncthreads();
    // pass 2: normalize in place (lanes walk contiguous channels -> conflict-free)
    if (tid < 192) {
      int c0 = tid * 2;
      float g0 = gg[c0], g1 = gg[c0 + 1], b0 = bb[c0], b1 = bb[c0 + 1];
      const float* st = (const float*)(smem + STATS_OFF);
      for (int p = 0; p < 64; ++p) {
        unsigned int* addr = (unsigned int*)(xn + p * XN_STR + c0);
        unsigned int v = *addr;
        float mean = st[p * 2], rstd = st[p * 2 + 1];
        float f0 = (bf2f(v & 0xffffu) - mean) * rstd * g0 + b0;
        float f1 = (bf2f(v >> 16) - mean) * rstd * g1 + b1;
        *addr = (unsigned int)f2bf(f0) | ((unsigned int)f2bf(f1) << 16);
      }
    }
    __syncthreads();
  }

  // ---------------- heads loop ----------------
  f32x4 outacc[6][4];
#pragma unroll
  for (int nn = 0; nn < 6; ++nn)
#pragma unroll
    for (int m = 0; m < 4; ++m) outacc[nn][m] = fzero;

  for (int h = 0; h < HEADS; ++h) {
    // --- Q (waves 0,1) / K (waves 2,3): each wave owns one 16-col n-tile -> weights loaded once ---
    {
      const unsigned short* wsrc = (wv < 2) ? wqb : wkvb;
      const unsigned short* asrc = (const unsigned short*)(smem + ((wv < 2) ? XN_OFF : SKN_OFF));
      const int nt = wv & 1;
      const int orow = h * 32 + nt * 16 + l15;   // weight row = output channel
      s16x8 bfr[12];
#pragma unroll
      for (int k = 0; k < 12; ++k)
        bfr[k] = *(const s16x8*)(wsrc + (size_t)orow * C + k * 32 + kco);
      f32x4 acc[4] = {fzero, fzero, fzero, fzero};
#pragma unroll
      for (int k = 0; k < 12; ++k) {
#pragma unroll
        for (int m = 0; m < 4; ++m) {
          s16x8 a = *(const s16x8*)(asrc + (m * 16 + l15) * XN_STR + k * 32 + kco);
          acc[m] = MFMA(a, bfr[k], acc[m]);
        }
      }
      unsigned short* dst = (unsigned short*)(smem + ((wv < 2) ? QH_OFF : KH_OFF));
      const float scl = (wv < 2) ? QSCALE : 1.0f;
#pragma unroll
      for (int m = 0; m < 4; ++m)
#pragma unroll
        for (int j = 0; j < 4; ++j)
          dst[(m * 16 + lg * 4 + j) * QH_STR + nt * 16 + l15] = f2bf(acc[m][j] * scl);
    }
    // --- V^T (all waves): weights as A-operand so D = V^T directly ---
    {
      const int mv = wv & 1;
      const int nbase = (wv >> 1) * 2;
      const int arow = 384 + h * 32 + mv * 16 + l15;   // Wkv row for V
      s16x8 af[12];
#pragma unroll
      for (int k = 0; k < 12; ++k)
        af[k] = *(const s16x8*)(wkvb + (size_t)arow * C + k * 32 + kco);
      const unsigned short* sk = (const unsigned short*)(smem + SKN_OFF);
      f32x4 acc[2] = {fzero, fzero};
#pragma unroll
      for (int k = 0; k < 12; ++k) {
#pragma unroll
        for (int n = 0; n < 2; ++n) {
          s16x8 b = *(const s16x8*)(sk + ((nbase + n) * 16 + l15) * XN_STR + k * 32 + kco);
          acc[n] = MFMA(af[k], b, acc[n]);
        }
      }
      unsigned short* vt = (unsigned short*)(smem + VT_OFF);
#pragma unroll
      for (int n = 0; n < 2; ++n)
#pragma unroll
        for (int j = 0; j < 4; ++j)
          vt[(mv * 16 + lg * 4 + j) * VT_STR + (nbase + n) * 16 + l15] = f2bf(acc[n][j]);
    }
    __syncthreads();
    // --- S = Q K^T (wave wv owns q-row tile wv), softmax, write P ---
    {
      const unsigned short* qh = (const unsigned short*)(smem + QH_OFF);
      const unsigned short* kh = (const unsigned short*)(smem + KH_OFF);
      s16x8 aq = *(const s16x8*)(qh + (wv * 16 + l15) * QH_STR + kco);
      f32x4 sv[4];
#pragma unroll
      for (int n = 0; n < 4; ++n) {
        s16x8 bk = *(const s16x8*)(kh + (n * 16 + l15) * QH_STR + kco);
        sv[n] = MFMA(aq, bk, fzero);
      }
      unsigned short* pb = (unsigned short*)(smem + P_OFF);
#pragma unroll
      for (int j = 0; j < 4; ++j) {
        float mx = fmaxf(fmaxf(sv[0][j], sv[1][j]), fmaxf(sv[2][j], sv[3][j]));
#pragma unroll
        for (int msk = 1; msk < 16; msk <<= 1) mx = fmaxf(mx, __shfl_xor(mx, msk));
        float e0 = __expf(sv[0][j] - mx);
        float e1 = __expf(sv[1][j] - mx);
        float e2 = __expf(sv[2][j] - mx);
        float e3 = __expf(sv[3][j] - mx);
        float sum = e0 + e1 + e2 + e3;
#pragma unroll
        for (int msk = 1; msk < 16; msk <<= 1) sum += __shfl_xor(sum, msk);
        float inv = 1.0f / sum;
        int prow = (wv * 16 + lg * 4 + j) * P_STR + l15;
        pb[prow + 0]  = f2bf(e0 * inv);
        pb[prow + 16] = f2bf(e1 * inv);
        pb[prow + 32] = f2bf(e2 * inv);
        pb[prow + 48] = f2bf(e3 * inv);
      }
    }
    __syncthreads();
    // --- O_h = P V^T  -> OH (reuses QH space; safe: barrier above drained QH reads) ---
    {
      const unsigned short* pb = (const unsigned short*)(smem + P_OFF);
      const unsigned short* vt = (const unsigned short*)(smem + VT_OFF);
      f32x4 o[2] = {fzero, fzero};
#pragma unroll
      for (int k = 0; k < 2; ++k) {
        s16x8 ap = *(const s16x8*)(pb + (wv * 16 + l15) * P_STR + k * 32 + kco);
#pragma unroll
        for (int n = 0; n < 2; ++n) {
          s16x8 bv = *(const s16x8*)(vt + (n * 16 + l15) * VT_STR + k * 32 + kco);
          o[n] = MFMA(ap, bv, o[n]);
        }
      }
      unsigned short* oh = (unsigned short*)(smem + QH_OFF);
#pragma unroll
      for (int n = 0; n < 2; ++n)
#pragma unroll
        for (int j = 0; j < 4; ++j)
          oh[(wv * 16 + lg * 4 + j) * QH_STR + n * 16 + l15] = f2bf(o[n][j]);
    }
    __syncthreads();
    // --- fused out-GEMM: outacc += O_h * Wout_h^T (wave owns 6 n-tiles -> B-frags unique) ---
    {
      const unsigned short* oh = (const unsigned short*)(smem + QH_OFF);
      s16x8 af2[4];
#pragma unroll
      for (int m = 0; m < 4; ++m)
        af2[m] = *(const s16x8*)(oh + (m * 16 + l15) * QH_STR + kco);
#pragma unroll
      for (int nn = 0; nn < 6; ++nn) {
        int ccol = (wv * 6 + nn) * 16 + l15;
        s16x8 bw = *(const s16x8*)(woutb + (size_t)ccol * INNER + h * 32 + kco);
#pragma unroll
        for (int m = 0; m < 4; ++m)
          outacc[nn][m] = MFMA(af2[m], bw, outacc[nn][m]);
      }
    }
    __syncthreads();
  }

  // ---------------- epilogue: transpose via LDS, coalesced store ----------------
  float* outf = (float*)smem;  // overlays XN+SKN (dead)
#pragma unroll
  for (int nn = 0; nn < 6; ++nn) {
    int ccol = (wv * 6 + nn) * 16 + l15;
    float bo = bout[ccol];
#pragma unroll
    for (int m = 0; m < 4; ++m)
#pragma unroll
      for (int j = 0; j < 4; ++j)
        outf[(m * 16 + lg * 4 + j) * OUTF_STR + ccol] = outacc[nn][m][j] + bo;
  }
  __syncthreads();
  float* obase = out + img_off + (size_t)(Y0 + (lane >> 3)) * WIMG + X0 + (lane & 7);
  for (int i = 0; i < 96; ++i) {
    int c = wv * 96 + i;
    obase[(size_t)c * HW] = outf[lane * OUTF_STR + c];
  }
}

extern "C" void kernel_launch(void* const* d_in, const int* in_sizes, int n_in,
                              void* d_out, int out_size, void* d_ws, size_t ws_size,
                              hipStream_t stream) {
  const float* x    = (const float*)d_in[0];
  const float* skip = (const float*)d_in[1];
  const float* gq   = (const float*)d_in[2];
  const float* bq   = (const float*)d_in[3];
  const float* gkv  = (const float*)d_in[4];
  const float* bkv  = (const float*)d_in[5];
  const float* Wq   = (const float*)d_in[6];
  const float* Wkv  = (const float*)d_in[7];
  const float* Wout = (const float*)d_in[8];
  const float* bout = (const float*)d_in[9];
  float* out = (float*)d_out;

  unsigned short* wqb   = (unsigned short*)d_ws;       // 147456 bf16
  unsigned short* wkvb  = wqb + 147456;                // 294912 bf16
  unsigned short* woutb = wkvb + 294912;               // 147456 bf16

  hipFuncSetAttribute((const void*)fused_win_attn,
                      hipFuncAttributeMaxDynamicSharedMemorySize, LDS_BYTES);

  cvt_bf16_kernel<<<144, 256, 0, stream>>>(Wq, wqb, 147456);
  cvt_bf16_kernel<<<288, 256, 0, stream>>>(Wkv, wkvb, 294912);
  cvt_bf16_kernel<<<144, 256, 0, stream>>>(Wout, woutb, 147456);

  fused_win_attn<<<2048, 256, LDS_BYTES, stream>>>(
      x, skip, gq, bq, gkv, bkv, wqb, wkvb, woutb, bout, out);
}

// Round 2
// 531.682 us; speedup vs baseline: 1.9082x; 1.9082x over previous
//
#include <hip/hip_runtime.h>
#include <stdint.h>

typedef __attribute__((ext_vector_type(4))) float f32x4;
typedef __attribute__((ext_vector_type(8))) short s16x8;
typedef unsigned int u32;
typedef unsigned short u16;

#define DEVFN static __device__ __forceinline__

constexpr int C = 384;
constexpr int WIMG = 128;
constexpr int HW = 128 * 128;
constexpr float EPS = 1e-5f;
constexpr float QSCALE = 0.17677669529663687f;  // 1/sqrt(32)

// ---- LDS regions (bytes). Total = exactly 160 KiB ----
constexpr int R1 = 0;        // XW raw-x bf16 [64][384] swz -> later Q -> later outf(f32)
constexpr int R2 = 49152;    // SKW raw-skip -> later VT [384 dh][64 tok] swz
constexpr int R3 = 98304;    // K [64][384] swz
constexpr int PR = 147456;   // 16 KB: LN stats/red scratch; later 2x 8 KB per-head P/OH
constexpr int LDS_BYTES = 163840;

DEVFN u16 f2bf(float f) {
  union { float f; u32 u; } v; v.f = f;
  u32 r = v.u + 0x7fffu + ((v.u >> 16) & 1u);  // RNE
  return (u16)(r >> 16);
}
DEVFN f32x4 MFMA(s16x8 a, s16x8 b, f32x4 c) {
  return __builtin_amdgcn_mfma_f32_16x16x32_bf16(a, b, c, 0, 0, 0);
}
// XOR-swizzled addresses: row-stride 768B ([64][384] bf16) and 128B ([*][64] bf16)
DEVFN int adr768(int base, int row, int b) { return base + row * 768 + (b ^ ((row & 7) << 4)); }
DEVFN int adr128(int base, int row, int b) { return base + row * 128 + (b ^ ((row & 7) << 4)); }

// ---------------- prep kernels ----------------
__global__ void cvt_bf16_kernel(const float* __restrict__ src, u16* __restrict__ dst, int n) {
  int i = (blockIdx.x * blockDim.x + threadIdx.x) * 4;
  if (i + 3 < n) {
    f32x4 v = *(const f32x4*)(src + i);
    u32* d = (u32*)(dst + i);
    d[0] = (u32)f2bf(v[0]) | ((u32)f2bf(v[1]) << 16);
    d[1] = (u32)f2bf(v[2]) | ((u32)f2bf(v[3]) << 16);
  }
}

// Fold LN gamma (and QSCALE) into weights; emit per-row sums sg = s*sum(W*g), sb = s*sum(W*b)
__global__ void fold_ln_weights(const float* __restrict__ Wq, const float* __restrict__ Wkv,
                                const float* __restrict__ gq, const float* __restrict__ bq,
                                const float* __restrict__ gkv, const float* __restrict__ bkv,
                                u16* __restrict__ wqb, u16* __restrict__ wkb, u16* __restrict__ wvb,
                                float* __restrict__ sg_all, float* __restrict__ sb_all) {
  int r = blockIdx.x * 4 + (threadIdx.x >> 6);  // 1152 rows: Q 0..383, K 384..767, V 768..1151
  int lane = threadIdx.x & 63;
  const float* src; const float* g; const float* b; u16* dst; float scale;
  if (r < 384) { src = Wq + (size_t)r * C; g = gq; b = bq; dst = wqb + (size_t)r * C; scale = QSCALE; }
  else {
    src = Wkv + (size_t)(r - 384) * C; g = gkv; b = bkv; scale = 1.f;
    dst = (r < 768) ? wkb + (size_t)(r - 384) * C : wvb + (size_t)(r - 768) * C;
  }
  float sg = 0.f, sb = 0.f;
#pragma unroll
  for (int i = 0; i < 6; ++i) {
    int c = lane + i * 64;
    float wv = src[c], gg = g[c];
    sg += wv * gg; sb += wv * b[c];
    dst[c] = f2bf(wv * gg * scale);
  }
#pragma unroll
  for (int m = 1; m < 64; m <<= 1) { sg += __shfl_xor(sg, m); sb += __shfl_xor(sb, m); }
  if (lane == 0) { sg_all[r] = sg * scale; sb_all[r] = sb * scale; }
}

// ---------------- fused kernel ----------------
__launch_bounds__(512, 2)
__global__ void fused_win_attn(
    const float* __restrict__ x, const float* __restrict__ skip,
    const u16* __restrict__ wqb, const u16* __restrict__ wkb,
    const u16* __restrict__ wvb, const u16* __restrict__ wob,
    const float* __restrict__ sg_all, const float* __restrict__ sb_all,
    const float* __restrict__ bout, float* __restrict__ out) {
  extern __shared__ char smem[];
  const int tid = threadIdx.x;
  const int lane = tid & 63;
  const int w = tid >> 6;         // wave 0..7
  const int l15 = lane & 15;
  const int lg = lane >> 4;       // 0..3
  const int kco = lg * 8;         // k-chunk short offset within K=32 step

  // bijective XCD swizzle: each XCD gets one batch image (256 consecutive windows)
  const int bid = blockIdx.x;
  const int win = (bid & 7) * 256 + (bid >> 3);
  const int bimg = win >> 8;
  const int Y0 = ((win >> 4) & 15) * 8;
  const int X0 = (win & 15) * 8;
  const size_t img_off = (size_t)bimg * C * HW;

  const f32x4 fzero = {0.f, 0.f, 0.f, 0.f};

  float* stats_x = (float*)(smem + PR);          // [64][2] mean,rstd
  float* stats_s = (float*)(smem + PR + 512);
  float* red = (float*)(smem + PR + 1024);       // [512][2]

  const int p = tid & 63;    // pixel/token 0..63 (row-major y*8+x)
  const int g8 = tid >> 6;   // channel group 0..7 (48 ch each)
  const int yy = p >> 3, xx = p & 7;

  // ---------------- load raw x/skip -> bf16 LDS + LN stats ----------------
  for (int tt = 0; tt < 2; ++tt) {
    const float* src = tt ? skip : x;
    const int RB = tt ? R2 : R1;
    const float* gb = src + img_off + (size_t)(Y0 + yy) * WIMG + X0 + xx;
    float s = 0.f, q = 0.f;
#pragma unroll
    for (int i = 0; i < 24; ++i) {
      int c0 = g8 * 48 + i * 2;
      float v0 = gb[(size_t)c0 * HW];
      float v1 = gb[(size_t)c0 * HW + HW];
      s += v0 + v1; q += v0 * v0 + v1 * v1;
      *(u32*)(smem + adr768(RB, p, c0 * 2)) = (u32)f2bf(v0) | ((u32)f2bf(v1) << 16);
    }
    red[tid * 2] = s; red[tid * 2 + 1] = q;
    __syncthreads();
    if (tid < 64) {
      float sm = 0.f, sq = 0.f;
#pragma unroll
      for (int gg = 0; gg < 8; ++gg) { sm += red[(gg * 64 + tid) * 2]; sq += red[(gg * 64 + tid) * 2 + 1]; }
      float mean = sm * (1.f / 384.f);
      float var = sq * (1.f / 384.f) - mean * mean;
      float* st = tt ? stats_s : stats_x;
      st[tid * 2] = mean; st[tid * 2 + 1] = 1.f / sqrtf(var + EPS);
    }
    __syncthreads();
  }

  // ---------------- K = LN(skip) @ Wk^T  (R2 -> R3), all heads ----------------
  {
    f32x4 acc[3][4];
#pragma unroll
    for (int nn = 0; nn < 3; ++nn)
#pragma unroll
      for (int m = 0; m < 4; ++m) acc[nn][m] = fzero;
#pragma unroll
    for (int k = 0; k < 12; ++k) {
      s16x8 A[4];
#pragma unroll
      for (int m = 0; m < 4; ++m)
        A[m] = *(const s16x8*)(smem + adr768(R2, m * 16 + l15, (k * 32 + kco) * 2));
#pragma unroll
      for (int nn = 0; nn < 3; ++nn) {
        s16x8 B = *(const s16x8*)(wkb + (size_t)((3 * w + nn) * 16 + l15) * C + k * 32 + kco);
#pragma unroll
        for (int m = 0; m < 4; ++m) acc[nn][m] = MFMA(A[m], B, acc[nn][m]);
      }
    }
    float sg3[3], sb3[3];
#pragma unroll
    for (int nn = 0; nn < 3; ++nn) {
      int o = (3 * w + nn) * 16 + l15;
      sg3[nn] = sg_all[384 + o]; sb3[nn] = sb_all[384 + o];
    }
#pragma unroll
    for (int m = 0; m < 4; ++m)
#pragma unroll
      for (int j = 0; j < 4; ++j) {
        int tok = m * 16 + lg * 4 + j;
        float mn = stats_s[tok * 2], rs = stats_s[tok * 2 + 1];
#pragma unroll
        for (int nn = 0; nn < 3; ++nn) {
          int o = (3 * w + nn) * 16 + l15;
          float val = rs * acc[nn][m][j] - rs * mn * sg3[nn] + sb3[nn];
          *(u16*)(smem + adr768(R3, tok, o * 2)) = f2bf(val);
        }
      }
  }

  // ---------------- VT = Wv @ LN(skip)^T  (R2 -> regs -> R2) ----------------
  {
    f32x4 acc[3][4];  // [mm = dh-tile][n = tok-tile]
#pragma unroll
    for (int mm = 0; mm < 3; ++mm)
#pragma unroll
      for (int n = 0; n < 4; ++n) acc[mm][n] = fzero;
#pragma unroll
    for (int k = 0; k < 12; ++k) {
      s16x8 Bv[4];
#pragma unroll
      for (int n = 0; n < 4; ++n)
        Bv[n] = *(const s16x8*)(smem + adr768(R2, n * 16 + l15, (k * 32 + kco) * 2));
#pragma unroll
      for (int mm = 0; mm < 3; ++mm) {
        s16x8 A = *(const s16x8*)(wvb + (size_t)((3 * w + mm) * 16 + l15) * C + k * 32 + kco);
#pragma unroll
        for (int n = 0; n < 4; ++n) acc[mm][n] = MFMA(A, Bv[n], acc[mm][n]);
      }
    }
    float mn4[4], rs4[4];
#pragma unroll
    for (int n = 0; n < 4; ++n) {
      int tok = n * 16 + l15;
      mn4[n] = stats_s[tok * 2]; rs4[n] = stats_s[tok * 2 + 1];
    }
    __syncthreads();  // all waves done reading SKW; safe to overwrite R2 with VT
#pragma unroll
    for (int mm = 0; mm < 3; ++mm)
#pragma unroll
      for (int j = 0; j < 4; ++j) {
        int dh = (3 * w + mm) * 16 + lg * 4 + j;
        float sg = sg_all[768 + dh], sb = sb_all[768 + dh];
#pragma unroll
        for (int n = 0; n < 4; ++n) {
          int tok = n * 16 + l15;
          float val = rs4[n] * acc[mm][n][j] - rs4[n] * mn4[n] * sg + sb;
          *(u16*)(smem + adr128(R2, dh, tok * 2)) = f2bf(val);
        }
      }
  }

  // ---------------- Q = LN(x) @ Wq^T * scale  (R1 -> regs -> R1) ----------------
  {
    f32x4 acc[3][4];
#pragma unroll
    for (int nn = 0; nn < 3; ++nn)
#pragma unroll
      for (int m = 0; m < 4; ++m) acc[nn][m] = fzero;
#pragma unroll
    for (int k = 0; k < 12; ++k) {
      s16x8 A[4];
#pragma unroll
      for (int m = 0; m < 4; ++m)
        A[m] = *(const s16x8*)(smem + adr768(R1, m * 16 + l15, (k * 32 + kco) * 2));
#pragma unroll
      for (int nn = 0; nn < 3; ++nn) {
        s16x8 B = *(const s16x8*)(wqb + (size_t)((3 * w + nn) * 16 + l15) * C + k * 32 + kco);
#pragma unroll
        for (int m = 0; m < 4; ++m) acc[nn][m] = MFMA(A[m], B, acc[nn][m]);
      }
    }
    float sg3[3], sb3[3];
#pragma unroll
    for (int nn = 0; nn < 3; ++nn) {
      int o = (3 * w + nn) * 16 + l15;
      sg3[nn] = sg_all[o]; sb3[nn] = sb_all[o];
    }
    __syncthreads();  // all waves done reading XW; safe to overwrite R1 with Q
#pragma unroll
    for (int m = 0; m < 4; ++m)
#pragma unroll
      for (int j = 0; j < 4; ++j) {
        int tok = m * 16 + lg * 4 + j;
        float mn = stats_x[tok * 2], rs = stats_x[tok * 2 + 1];
#pragma unroll
        for (int nn = 0; nn < 3; ++nn) {
          int o = (3 * w + nn) * 16 + l15;
          float val = rs * acc[nn][m][j] - rs * mn * sg3[nn] + sb3[nn];
          *(u16*)(smem + adr768(R1, tok, o * 2)) = f2bf(val);
        }
      }
  }
  __syncthreads();  // Q/K/VT all visible

  // ---------------- attention: 2 heads concurrently (waves 0-3 even, 4-7 odd) ----------------
  f32x4 outacc[6][4];
#pragma unroll
  for (int nn = 0; nn < 6; ++nn)
#pragma unroll
    for (int m = 0; m < 4; ++m) outacc[nn][m] = fzero;

  const int wq = w & 3;
  const int hpar = (w >= 4) ? 1 : 0;
  char* PH = smem + PR + hpar * 8192;  // per-head-pair P([64][64] swz) / OH([64][40] pad)

  for (int t = 0; t < 6; ++t) {
    const int ha = 2 * t + hpar;
    // prefetch Wout B-frags for this head (used 3 barriers later)
    s16x8 WB[6];
#pragma unroll
    for (int nn = 0; nn < 6; ++nn)
      WB[nn] = *(const s16x8*)(wob + (size_t)((wq * 6 + nn) * 16 + l15) * C + ha * 32 + kco);

    // --- S = Q K^T, softmax, P (wave-local rows: no barrier needed before O) ---
    {
      s16x8 aq = *(const s16x8*)(smem + adr768(R1, wq * 16 + l15, (ha * 32 + kco) * 2));
      f32x4 sv[4];
#pragma unroll
      for (int n = 0; n < 4; ++n) {
        s16x8 bk = *(const s16x8*)(smem + adr768(R3, n * 16 + l15, (ha * 32 + kco) * 2));
        sv[n] = MFMA(aq, bk, fzero);
      }
#pragma unroll
      for (int j = 0; j < 4; ++j) {
        float mx = fmaxf(fmaxf(sv[0][j], sv[1][j]), fmaxf(sv[2][j], sv[3][j]));
#pragma unroll
        for (int msk = 1; msk < 16; msk <<= 1) mx = fmaxf(mx, __shfl_xor(mx, msk));
        float e0 = __expf(sv[0][j] - mx);
        float e1 = __expf(sv[1][j] - mx);
        float e2 = __expf(sv[2][j] - mx);
        float e3 = __expf(sv[3][j] - mx);
        float sum = e0 + e1 + e2 + e3;
#pragma unroll
        for (int msk = 1; msk < 16; msk <<= 1) sum += __shfl_xor(sum, msk);
        float inv = 1.0f / sum;
        int row = wq * 16 + lg * 4 + j;
        int sw = (row & 7) << 4;
        *(u16*)(PH + row * 128 + (((0 * 16 + l15) * 2) ^ sw)) = f2bf(e0 * inv);
        *(u16*)(PH + row * 128 + (((1 * 16 + l15) * 2) ^ sw)) = f2bf(e1 * inv);
        *(u16*)(PH + row * 128 + (((2 * 16 + l15) * 2) ^ sw)) = f2bf(e2 * inv);
        *(u16*)(PH + row * 128 + (((3 * 16 + l15) * 2) ^ sw)) = f2bf(e3 * inv);
      }
    }
    // --- O = P VT (reads own wave's P rows) ---
    f32x4 ov[2] = {fzero, fzero};
#pragma unroll
    for (int ks = 0; ks < 2; ++ks) {
      int prow = wq * 16 + l15;
      s16x8 ap = *(const s16x8*)(PH + prow * 128 + (((ks * 32 + kco) * 2) ^ ((prow & 7) << 4)));
#pragma unroll
      for (int n = 0; n < 2; ++n) {
        s16x8 bv = *(const s16x8*)(smem + adr128(R2, ha * 32 + n * 16 + l15, (ks * 32 + kco) * 2));
        ov[n] = MFMA(ap, bv, ov[n]);
      }
    }
    __syncthreads();  // all P reads complete before OH overwrites region
#pragma unroll
    for (int n = 0; n < 2; ++n)
#pragma unroll
      for (int j = 0; j < 4; ++j)
        *(u16*)(PH + (wq * 16 + lg * 4 + j) * 80 + (n * 16 + l15) * 2) = f2bf(ov[n][j]);
    __syncthreads();  // OH visible to all waves
    // --- fused out-GEMM: outacc += OH * Wout_h^T ---
    {
      s16x8 ao[4];
#pragma unroll
      for (int m = 0; m < 4; ++m)
        ao[m] = *(const s16x8*)(PH + (m * 16 + l15) * 80 + kco * 2);
#pragma unroll
      for (int nn = 0; nn < 6; ++nn)
#pragma unroll
        for (int m = 0; m < 4; ++m)
          outacc[nn][m] = MFMA(ao[m], WB[nn], outacc[nn][m]);
    }
    __syncthreads();  // OH reads done before next head's P write
  }

  // ---------------- epilogue: reduce wave-pairs, add bias, coalesced store ----------------
  float* outf = (float*)smem;  // f32 [64][385] overlays R1..R3 (dead)
  if (w < 4) {
#pragma unroll
    for (int nn = 0; nn < 6; ++nn) {
      int o = (wq * 6 + nn) * 16 + l15;
      float bo = bout[o];
#pragma unroll
      for (int m = 0; m < 4; ++m)
#pragma unroll
        for (int j = 0; j < 4; ++j)
          outf[(m * 16 + lg * 4 + j) * 385 + o] = outacc[nn][m][j] + bo;
    }
  }
  __syncthreads();
  if (w >= 4) {
#pragma unroll
    for (int nn = 0; nn < 6; ++nn) {
      int o = (wq * 6 + nn) * 16 + l15;
#pragma unroll
      for (int m = 0; m < 4; ++m)
#pragma unroll
        for (int j = 0; j < 4; ++j)
          outf[(m * 16 + lg * 4 + j) * 385 + o] += outacc[nn][m][j];
    }
  }
  __syncthreads();
  {
    float* ob = out + img_off + (size_t)(Y0 + yy) * WIMG + X0 + xx;
#pragma unroll
    for (int i = 0; i < 48; ++i) {
      int c = g8 * 48 + i;
      ob[(size_t)c * HW] = outf[p * 385 + c];
    }
  }
}

extern "C" void kernel_launch(void* const* d_in, const int* in_sizes, int n_in,
                              void* d_out, int out_size, void* d_ws, size_t ws_size,
                              hipStream_t stream) {
  const float* x    = (const float*)d_in[0];
  const float* skip = (const float*)d_in[1];
  const float* gq   = (const float*)d_in[2];
  const float* bq   = (const float*)d_in[3];
  const float* gkv  = (const float*)d_in[4];
  const float* bkv  = (const float*)d_in[5];
  const float* Wq   = (const float*)d_in[6];
  const float* Wkv  = (const float*)d_in[7];
  const float* Wout = (const float*)d_in[8];
  const float* bout = (const float*)d_in[9];
  float* out = (float*)d_out;

  char* ws = (char*)d_ws;
  u16* wqb = (u16*)(ws);                  // 384*384 bf16
  u16* wkb = (u16*)(ws + 294912);
  u16* wvb = (u16*)(ws + 589824);
  u16* wob = (u16*)(ws + 884736);
  float* sg_all = (float*)(ws + 1179648); // [1152]
  float* sb_all = (float*)(ws + 1184256); // [1152]

  hipFuncSetAttribute((const void*)fused_win_attn,
                      hipFuncAttributeMaxDynamicSharedMemorySize, LDS_BYTES);

  fold_ln_weights<<<288, 256, 0, stream>>>(Wq, Wkv, gq, bq, gkv, bkv, wqb, wkb, wvb, sg_all, sb_all);
  cvt_bf16_kernel<<<144, 256, 0, stream>>>(Wout, wob, 147456);

  fused_win_attn<<<2048, 512, LDS_BYTES, stream>>>(
      x, skip, wqb, wkb, wvb, wob, sg_all, sb_all, bout, out);
}